// Round 5
// baseline (219.331 us; speedup 1.0000x reference)
//
#include <hip/hip_runtime.h>

// out = x + 42.0f over 33,554,432 fp32. Memory-bound streaming kernel.
// 268 MB compulsory traffic; kernel floor ~42.6 us @ 6.3 TB/s copy ceiling.
// Harness adds ~160 us fixed cost (2 x 512 MiB poison fills @ ~80 us each,
// in rocprof every round) inside the timed region -> total floor ~203 us.
//
// Ladder (kernel slice): NT+NT one-shot 256thr MLP4 = ~56 us (best, R1);
// block 1024 neutral (R4); plain loads +14 us (R3); grid-stride +14 us (R2).
// Geometry is a non-lever. Load policy settled: NT loads win.
// THIS ROUND isolates the last untested corner: store policy under NT loads.
// Evidence for plain stores: harness fills sustain 6.7 TB/s with plain
// stores (best BW on this box); full-line coalesced writes allocate without
// read traffic, and L2 write-buffering may smooth HBM scheduling that NT
// (L2-bypass) stores forgo.
// One variable vs R1: stores NT -> plain. Loads stay NT, one-shot 8192x256.

typedef float floatx4 __attribute__((ext_vector_type(4)));

__global__ __launch_bounds__(256) void add42_kernel(
    const floatx4* __restrict__ x, floatx4* __restrict__ out, int n4) {
    int base = blockIdx.x * (blockDim.x * 4) + threadIdx.x;
    int i0 = base;
    int i1 = base + blockDim.x;
    int i2 = base + 2 * blockDim.x;
    int i3 = base + 3 * blockDim.x;

    if (i3 < n4) {
        // Four independent NT loads in flight, then four plain stores.
        floatx4 a = __builtin_nontemporal_load(&x[i0]);
        floatx4 b = __builtin_nontemporal_load(&x[i1]);
        floatx4 c = __builtin_nontemporal_load(&x[i2]);
        floatx4 d = __builtin_nontemporal_load(&x[i3]);
        a += 42.0f;
        b += 42.0f;
        c += 42.0f;
        d += 42.0f;
        out[i0] = a;
        out[i1] = b;
        out[i2] = c;
        out[i3] = d;
    } else {
        // Tail (never taken for the 8192x4096 shape: n4 % 1024 == 0).
        for (int i = i0; i < n4; i += blockDim.x) {
            floatx4 a = __builtin_nontemporal_load(&x[i]);
            a += 42.0f;
            out[i] = a;
        }
    }
}

extern "C" void kernel_launch(void* const* d_in, const int* in_sizes, int n_in,
                              void* d_out, int out_size, void* d_ws, size_t ws_size,
                              hipStream_t stream) {
    const floatx4* x = (const floatx4*)d_in[0];
    floatx4* out = (floatx4*)d_out;
    int n = in_sizes[0];              // 33,554,432 fp32
    int n4 = n >> 2;                  // 8,388,608 16B vectors
    int block = 256;
    int per_block = block * 4;        // 1024 vectors (16 KB) per block
    int grid = (n4 + per_block - 1) / per_block;  // 8,192 blocks
    add42_kernel<<<grid, block, 0, stream>>>(x, out, n4);
}